// Round 1
// baseline (129.963 us; speedup 1.0000x reference)
//
#include <hip/hip_runtime.h>
#include <hip/hip_fp16.h>
#include <math.h>

#define NPATH 1536
#define SEGS  65        // 0..64 active-channel counts
#define NB    160
#define NA    160
#define CW    32        // chunks (waves) per (z,a)
#define PPW   5         // pairs per wave = NB/CW

// Pre-contracted radial table in d_ws:
//   PC[z*NB+b][seg][256 u32]  (1 KB rows, 21.3 MB total)
// slot t = lane*4 + j, packed u32 = {fp16 slope | fp16 icpt}:
//   lane  0..15 (l0 task u=lane): j0 = A(u)->T0 ; j1..3 = B(u,xyz)->T1c
//   lane 16..63 (l1 task u=(lane-16)/3, part=(lane-16)%3):
//     part0: j0 = C(u)->T0 ; j1..3 = D(u,xyz)->T1c
//     part1: j0..2 = E(u,xyz)->T2c ; j3 pad
//     part2: j0..2 = F(u,xyz)->T3c ; j3 pad
// T_k(u) for a pair = r*slope + icpt  (features already contracted over v).
__device__ float dg_thr[64];

#define SCL_A 0.17677669529663687f
#define SCL_B 0.6266570686577502f
#define SCL_C 0.2558286876965162f
#define SCL_D 0.125f
#define SCL_E 0.3133285343288751f
#define SCL_F 0.7674950309598664f

// blocks 0..639: one (z,b,half) each — build 65 segment rows by prefix over the
// threshold-sorted channel order (one ReLU channel flips per segment step).
// blocks 640..799: zero d_out.
__global__ __launch_bounds__(128) void k_pc(const float* __restrict__ feat,
                                            const float* __restrict__ W1,
                                            const float* __restrict__ b1,
                                            const float* __restrict__ W2,
                                            const float* __restrict__ b2,
                                            unsigned int* __restrict__ PC,
                                            float* __restrict__ out) {
    int bid = blockIdx.x, tid = threadIdx.x;
    if (bid >= 640) {
        out[(bid - 640) * 128 + tid] = 0.0f;
        return;
    }
    int zb = bid >> 1, half = bid & 1;
    int t  = half * 128 + tid;          // slot index 0..255 of the row

    __shared__ float fL[64], tvL[64], iwL[64], ibL[64], dwL[64], dbL[64];
    __shared__ int   ordL[64];
    __shared__ float hL[64][128];       // 32 KB: per-channel H, own column only

    if (tid < 64) {
        fL[tid] = feat[(size_t)zb * 64 + tid];
        float w = W1[tid], bb = b1[tid];
        tvL[tid] = (w != 0.0f) ? (-bb / w) : __builtin_inff();
    }
    __syncthreads();
    if (tid < 64) {
        float mine = tvL[tid];
        int rank = 0;
        for (int j2 = 0; j2 < 64; ++j2) {
            float o = tvL[j2];
            rank += (o < mine || (o == mine && j2 < tid)) ? 1 : 0;
        }
        float w = W1[tid], bb = b1[tid];
        // seg-0 active set: {w<0} u {w==0 && b>0}
        iwL[tid] = (w < 0.0f) ? w : 0.0f;
        ibL[tid] = (w < 0.0f) ? bb : ((w == 0.0f && bb > 0.0f) ? bb : 0.0f);
        // step s flips the channel with rank s-1: w>0 adds, w<0 removes
        ordL[rank] = tid;
        dwL[rank]  = fabsf(w);
        dbL[rank]  = (w > 0.0f) ? bb : ((w < 0.0f) ? -bb : 0.0f);
        if (bid == 0) dg_thr[tid] = mine;
    }
    __syncthreads();

    // slot -> path base/stride, feature component, folded scale
    int lane4 = t >> 2, j = t & 3;
    int pbase = 0, pstr = 1, comp = -1;
    float scl = 0.0f;                    // pad slots keep scl=0 -> row value 0
    if (lane4 < 16) {
        if (j == 0) { pbase = lane4 * 16;        scl = SCL_A; }
        else        { pbase = 256 + lane4 * 16;  comp = j - 1; scl = SCL_B; }
    } else {
        int lu = lane4 - 16, u = lu / 3, part = lu - u * 3;
        if (part == 0) {
            if (j == 0) { pbase = 512 + u * 16;             scl = SCL_C; }
            else        { pbase = 768 + u * 48; pstr = 3; comp = j - 1; scl = SCL_D; }
        } else if (part == 1) {
            if (j < 3)  { pbase = 768 + u * 48 + 1; pstr = 3; comp = j; scl = SCL_E; }
        } else {
            if (j < 3)  { pbase = 768 + u * 48 + 2; pstr = 3; comp = j; scl = SCL_F; }
        }
    }

    float fv[16];
    #pragma unroll
    for (int v = 0; v < 16; ++v)
        fv[v] = scl * ((comp < 0) ? fL[v] : fL[16 + v * 3 + comp]);

    float ib2 = 0.0f;                    // b2 contraction (seg-independent icpt)
    #pragma unroll
    for (int v = 0; v < 16; ++v) ib2 = fmaf(b2[pbase + v * pstr], fv[v], ib2);

    float slope = 0.0f, icpt = ib2;
    #pragma unroll 2
    for (int c = 0; c < 64; ++c) {
        const float* w2r = W2 + c * NPATH + pbase;
        float h = 0.0f;
        if (pstr == 1) {
            const float4* q = (const float4*)w2r;   // pbase % 4 == 0 here
            #pragma unroll
            for (int v4 = 0; v4 < 4; ++v4) {
                float4 w4 = q[v4];
                h = fmaf(w4.x, fv[v4 * 4 + 0], h);
                h = fmaf(w4.y, fv[v4 * 4 + 1], h);
                h = fmaf(w4.z, fv[v4 * 4 + 2], h);
                h = fmaf(w4.w, fv[v4 * 4 + 3], h);
            }
        } else {
            #pragma unroll
            for (int v = 0; v < 16; ++v) h = fmaf(w2r[v * 3], fv[v], h);
        }
        hL[c][tid] = h;
        slope = fmaf(iwL[c], h, slope);
        icpt  = fmaf(ibL[c], h, icpt);
    }
    // no barrier needed: prefix reads only this thread's own hL column

    unsigned int* rowp = PC + (size_t)zb * (SEGS * 256) + t;
    union { __half2 h; unsigned int u; } pk;
    pk.h = __halves2half2(__float2half(slope), __float2half(icpt));
    rowp[0] = pk.u;
    for (int s = 1; s < SEGS; ++s) {
        int c = ordL[s - 1];
        float h = hL[c][tid];
        slope = fmaf(dwL[s - 1], h, slope);
        icpt  = fmaf(dbL[s - 1], h, icpt);
        pk.h = __halves2half2(__float2half(slope), __float2half(icpt));
        rowp[(size_t)s * 256] = pk.u;
    }
}

static __device__ __forceinline__ float rcomb(unsigned int v, float r) {
    union { unsigned int u; __half2 h; } cv; cv.u = v;
    return fmaf(r, __low2float(cv.h), __high2float(cv.h));
}

__global__ __launch_bounds__(256, 4) void k_main(const float* __restrict__ geom,
                                                 const float* __restrict__ mask,
                                                 const unsigned int* __restrict__ PC,
                                                 float* __restrict__ out) {
    int wv   = threadIdx.x >> 6;
    int lane = threadIdx.x & 63;
    int gw   = blockIdx.x * 4 + wv;     // 4 waves of a block share za
    int chunk = gw & (CW - 1);
    int za    = gw >> 5;                // z*160 + a
    int z     = za / NA;

    __shared__ float sAcc[4][64];

    bool l0 = lane < 16;
    int  u = 0, part = 0;
    if (!l0) { int lu = lane - 16; u = lu / 3; part = lu - u * 3; }
    float zft = l0 ? 1.4142135623730951f : 2.0f;   // zero-radius norm ratio
    float thrv = dg_thr[lane];

    const float is30 = 0.18257418583505536f;  // 1/sqrt(30)
    const float is10 = 0.31622776601683794f;  // 1/sqrt(10)
    const float c1sh = 0.4886025119029199f;
    const float c21 = 1.0925484305920792f, c22 = 0.31539156525252005f, c23 = 0.5462742152960396f;

    // ---- geometry / segment for all PPW pairs ----
    int b0 = chunk * PPW;
    float rr[PPW], nxa[PPW], nya[PPW], nza[PPW], zfa[PPW];
    unsigned int rowo[PPW];
    #pragma unroll
    for (int it = 0; it < PPW; ++it) {
        const float* g = geom + ((size_t)za * NB + b0 + it) * 3;
        float gx = g[0], gy = g[1], gz = g[2];
        float r = sqrtf(gx * gx + gy * gy + gz * gz);
        bool zr = (r == 0.0f);
        float inv = zr ? 1.0f : (1.0f / r);
        nxa[it] = gx * inv; nya[it] = gy * inv; nza[it] = gz * inv;
        rr[it] = r;
        zfa[it] = zr ? zft : 1.0f;
        unsigned long long bm = __ballot(thrv < r);
        int s = __popcll(bm);
        rowo[it] = ((unsigned)(z * NB + b0 + it) * SEGS + (unsigned)s) * 256u
                 + (unsigned)(lane * 4);
    }

    float acc0 = 0.0f, acc1 = 0.0f, acc2 = 0.0f;

    // ---- software pipeline: one dwordx4 per lane per pair ----
    uint4 tb[2];
    tb[0] = *(const uint4*)(PC + rowo[0]);

    #pragma unroll
    for (int it = 0; it < PPW; ++it) {
        if (it + 1 < PPW) tb[(it + 1) & 1] = *(const uint4*)(PC + rowo[it + 1]);
        uint4 tt = tb[it & 1];
        float r = rr[it];
        float T0 = rcomb(tt.x, r);
        float T1 = rcomb(tt.y, r);
        float T2 = rcomb(tt.z, r);
        float T3 = rcomb(tt.w, r);

        float nx = nxa[it], ny = nya[it], nz = nza[it];
        float Y1_0 = c1sh * ny, Y1_1 = c1sh * nz, Y1_2 = c1sh * nx;
        float zf = zfa[it];

        if (l0) {
            // out(l0,u) partial: T0 + Y1 . T1vec
            float sl0 = T0;
            sl0 = fmaf(Y1_0, T1, sl0);
            sl0 = fmaf(Y1_1, T2, sl0);
            sl0 = fmaf(Y1_2, T3, sl0);
            acc0 = fmaf(sl0, zf, acc0);
        } else if (part == 0) {
            // T0 (C) + T1vec (D) terms of s_xyz
            float px = fmaf(Y1_0, T0, T1);
            float py = fmaf(Y1_1, T0, T2);
            float pz = fmaf(Y1_2, T0, T3);
            acc0 = fmaf(px, zf, acc0);
            acc1 = fmaf(py, zf, acc1);
            acc2 = fmaf(pz, zf, acc2);
        } else if (part == 1) {
            // T2vec (E) cross terms
            float px = fmaf(Y1_2, T1, -Y1_1 * T2);
            float py = fmaf(Y1_0, T2, -Y1_2 * T0);
            float pz = fmaf(Y1_1, T0, -Y1_0 * T1);
            acc0 = fmaf(px, zf, acc0);
            acc1 = fmaf(py, zf, acc1);
            acc2 = fmaf(pz, zf, acc2);
        } else {
            // T3vec (F) l=2 terms
            float Y2_0 = c21 * nx * ny;
            float Y2_1 = c21 * ny * nz;
            float Y2_2 = c22 * fmaf(3.0f, nz * nz, -1.0f);
            float Y2_3 = c21 * nx * nz;
            float Y2_4 = c23 * (nx * nx - ny * ny);
            float za_ = is10 * Y2_0, zb_ = is10 * Y2_1, zc_ = is10 * Y2_3;
            float zd_ = is30 * Y2_2, ze_ = is10 * Y2_4;
            float px = fmaf(-(zd_ + ze_), T0, fmaf(zb_, T1, za_ * T2));
            float py = fmaf(zb_, T0, fmaf(2.0f * zd_, T1, zc_ * T2));
            float pz = fmaf(za_, T0, fmaf(zc_, T1, (ze_ - zd_) * T2));
            acc0 = fmaf(px, zf, acc0);
            acc1 = fmaf(py, zf, acc1);
            acc2 = fmaf(pz, zf, acc2);
        }
    }

    // ---- combine the 3 l1 parts (lanes 16+3u+{0,1,2}) ----
    float ax = acc0 + __shfl_down(acc0, 1) + __shfl_down(acc0, 2);
    float ay = acc1 + __shfl_down(acc1, 1) + __shfl_down(acc1, 2);
    float az = acc2 + __shfl_down(acc2, 1) + __shfl_down(acc2, 2);
    if (l0) {
        sAcc[wv][lane] = acc0;
    } else if (part == 0) {
        int ob = 16 + u * 3;
        sAcc[wv][ob]     = ax;
        sAcc[wv][ob + 1] = ay;
        sAcc[wv][ob + 2] = az;
    }
    __syncthreads();
    if (threadIdx.x < 64) {
        float sum = sAcc[0][threadIdx.x] + sAcc[1][threadIdx.x]
                  + sAcc[2][threadIdx.x] + sAcc[3][threadIdx.x];
        sum *= mask[za];
        atomicAdd(&out[(size_t)za * 64 + threadIdx.x], sum);
    }
}

extern "C" void kernel_launch(void* const* d_in, const int* in_sizes, int n_in,
                              void* d_out, int out_size, void* d_ws, size_t ws_size,
                              hipStream_t stream) {
    (void)in_sizes; (void)n_in; (void)ws_size; (void)out_size;
    const float* feat = (const float*)d_in[0];
    const float* geom = (const float*)d_in[1];
    const float* mask = (const float*)d_in[2];
    const float* W1   = (const float*)d_in[3];
    const float* b1   = (const float*)d_in[4];
    const float* W2   = (const float*)d_in[5];
    const float* b2   = (const float*)d_in[6];
    float* out = (float*)d_out;
    unsigned int* PC = (unsigned int*)d_ws;   // 320*65*1024 B = 21.3 MB

    k_pc<<<800, 128, 0, stream>>>(feat, W1, b1, W2, b2, PC, out);  // 640 table + 160 zero
    k_main<<<2 * NA * CW / 4, 256, 0, stream>>>(geom, mask, PC, out);
}

// Round 2
// 111.645 us; speedup vs baseline: 1.1641x; 1.1641x over previous
//
#include <hip/hip_runtime.h>
#include <hip/hip_fp16.h>
#include <math.h>

#define NPATH 1536
#define SEGS  65        // 0..64 active-channel counts
#define NB    160
#define NA    160
#define CW    32        // chunks (waves) per (z,a)
#define PPW   5         // pairs per wave = NB/CW

// Pre-contracted radial table in d_ws:
//   PC[z*NB+b][seg][256 u32]  (1 KB rows, 21.3 MB total)
// slot t = lane*4 + j, packed u32 = {fp16 slope | fp16 icpt}:
//   lane  0..15 (l0 task u=lane): j0 = A(u)->T0 ; j1..3 = B(u,xyz)->T1c
//   lane 16..63 (l1 task u=(lane-16)/3, part=(lane-16)%3):
//     part0: j0 = C(u)->T0 ; j1..3 = D(u,xyz)->T1c
//     part1: j0..2 = E(u,xyz)->T2c ; j3 pad
//     part2: j0..2 = F(u,xyz)->T3c ; j3 pad
// T_k(u) for a pair = r*slope + icpt  (features already contracted over v).
//
// d_ws layout: [0, 21.3MB) PC ; [21.3MB, +1MB) W2G[t][v][c] (scl folded);
//              then B2T[v][t] (16 KB, scl folded).
#define PC_U32S   (320 * SEGS * 256)            // 5,324,800 u32
#define W2G_OFF   PC_U32S                        // in floats (4B units)
#define B2T_OFF   (W2G_OFF + 256 * 16 * 64)

__device__ float dg_thr[64];
__device__ float dg_iw[64], dg_ib[64], dg_dw[64], dg_db[64];
__device__ int   dg_ord[64];

#define SCL_A 0.17677669529663687f
#define SCL_B 0.6266570686577502f
#define SCL_C 0.2558286876965162f
#define SCL_D 0.125f
#define SCL_E 0.3133285343288751f
#define SCL_F 0.7674950309598664f

// slot t -> (path base, path stride, feature component, folded scale).
// comp == -1 -> feature fL[v]; else fL[16 + 3v + comp]. Pad slots: scl = 0.
static __device__ __forceinline__ void slot_map(int t, int& pbase, int& pstr,
                                                int& comp, float& scl) {
    int lane4 = t >> 2, j = t & 3;
    pbase = 0; pstr = 1; comp = -1; scl = 0.0f;
    if (lane4 < 16) {
        if (j == 0) { pbase = lane4 * 16;       scl = SCL_A; }
        else        { pbase = 256 + lane4 * 16; comp = j - 1; scl = SCL_B; }
    } else {
        int lu = lane4 - 16, u = lu / 3, part = lu - u * 3;
        if (part == 0) {
            if (j == 0) { pbase = 512 + u * 16;                       scl = SCL_C; }
            else        { pbase = 768 + u * 48; pstr = 3; comp = j - 1; scl = SCL_D; }
        } else if (part == 1) {
            if (j < 3)  { pbase = 768 + u * 48 + 1; pstr = 3; comp = j; scl = SCL_E; }
        } else {
            if (j < 3)  { pbase = 768 + u * 48 + 2; pstr = 3; comp = j; scl = SCL_F; }
        }
    }
}

// One-shot prep: blocks 0..255 gather W2 into W2G[t][v][c] (coalesced-on-c
// layout, scale folded; pad slots become zero rows) + B2T[v][t]; block 256
// computes the threshold-sorted channel order/deltas; blocks 257..336 zero out.
__global__ __launch_bounds__(256) void k_w2g(const float* __restrict__ W1,
                                             const float* __restrict__ b1,
                                             const float* __restrict__ W2,
                                             const float* __restrict__ b2,
                                             float* __restrict__ ws,
                                             float* __restrict__ out) {
    int bid = blockIdx.x, tid = threadIdx.x;
    if (bid == 256) {
        __shared__ float tvL[64];
        if (tid < 64) {
            float w = W1[tid], bb = b1[tid];
            tvL[tid] = (w != 0.0f) ? (-bb / w) : __builtin_inff();
        }
        __syncthreads();
        if (tid < 64) {
            float mine = tvL[tid];
            int rank = 0;
            for (int j2 = 0; j2 < 64; ++j2) {
                float o = tvL[j2];
                rank += (o < mine || (o == mine && j2 < tid)) ? 1 : 0;
            }
            float w = W1[tid], bb = b1[tid];
            // seg-0 active set: {w<0} u {w==0 && b>0}
            dg_iw[tid] = (w < 0.0f) ? w : 0.0f;
            dg_ib[tid] = (w < 0.0f) ? bb : ((w == 0.0f && bb > 0.0f) ? bb : 0.0f);
            // step s flips the channel with rank s-1: w>0 adds, w<0 removes
            dg_ord[rank] = tid;
            dg_dw[rank]  = fabsf(w);
            dg_db[rank]  = (w > 0.0f) ? bb : ((w < 0.0f) ? -bb : 0.0f);
            dg_thr[tid]  = mine;
        }
        return;
    }
    if (bid > 256) {                       // 80 blocks zero d_out (20480 floats)
        out[(bid - 257) * 256 + tid] = 0.0f;
        return;
    }
    int t = bid;
    int pbase, pstr, comp; float scl;
    slot_map(t, pbase, pstr, comp, scl);
    (void)comp;
    int c = tid & 63, vq = tid >> 6;
    float* W2G = ws + W2G_OFF;
    #pragma unroll
    for (int vv = 0; vv < 4; ++vv) {
        int v = vq * 4 + vv;
        float val = scl * W2[(size_t)c * NPATH + pbase + v * pstr];
        W2G[(size_t)((t << 4) + v) * 64 + c] = val;
    }
    if (tid < 16) {
        ws[B2T_OFF + tid * 256 + t] = scl * b2[pbase + tid * pstr];
    }
}

// Per (zb, half-row): phase 1 computes H[c][slot] with lanes=c and fully
// coalesced W2G loads; phase 2 (thread=slot) runs the 65-segment prefix and
// stores packed {fp16 slope | fp16 icpt} rows.
__global__ __launch_bounds__(128) void k_pc2(const float* __restrict__ feat,
                                             const float* __restrict__ ws,
                                             unsigned int* __restrict__ PC) {
    int bid = blockIdx.x;                 // 0..639
    int zb = bid >> 1, half = bid & 1;
    int tid = threadIdx.x, wv = tid >> 6, lane = tid & 63;

    __shared__ float hL[64][129];         // padded: conflict-free both phases
    __shared__ float fL[64], iwS[64], ibS[64], dwS[64], dbS[64];
    __shared__ int   ordS[64];

    if (tid < 64) {
        fL[tid]  = feat[(size_t)zb * 64 + tid];
        iwS[tid] = dg_iw[tid];  ibS[tid] = dg_ib[tid];
        dwS[tid] = dg_dw[tid];  dbS[tid] = dg_db[tid];
        ordS[tid] = dg_ord[tid];
    }
    __syncthreads();

    const float* W2G = ws + W2G_OFF;
    // ---- phase 1: wave wv computes 64 slots, lane = channel c ----
    #pragma unroll 2
    for (int i = 0; i < 64; ++i) {
        int lt = wv * 64 + i;
        int t  = half * 128 + lt;
        int pbase, pstr, comp; float scl;
        slot_map(t, pbase, pstr, comp, scl);
        (void)pbase; (void)pstr; (void)scl;   // folded into W2G already
        const float* wp = W2G + ((size_t)t << 10) + lane;
        float h = 0.0f;
        #pragma unroll
        for (int v = 0; v < 16; ++v) {
            float fvv = (comp < 0) ? fL[v] : fL[16 + 3 * v + comp];
            h = fmaf(wp[v << 6], fvv, h);     // 256B coalesced load
        }
        hL[lane][lt] = h;
    }
    __syncthreads();

    // ---- phase 2: thread = slot; seg-0 masked sums then incremental prefix ----
    int t = half * 128 + tid;
    int pbase, pstr, comp; float scl;
    slot_map(t, pbase, pstr, comp, scl);
    (void)pbase; (void)pstr; (void)scl;

    float ib2 = 0.0f;                     // b2 contraction (seg-independent)
    #pragma unroll
    for (int v = 0; v < 16; ++v) {
        float fvv = (comp < 0) ? fL[v] : fL[16 + 3 * v + comp];
        ib2 = fmaf(ws[B2T_OFF + v * 256 + t], fvv, ib2);
    }

    float slope = 0.0f, icpt = ib2;
    #pragma unroll 4
    for (int c = 0; c < 64; ++c) {
        float h = hL[c][tid];
        slope = fmaf(iwS[c], h, slope);
        icpt  = fmaf(ibS[c], h, icpt);
    }

    unsigned int* rowp = PC + (size_t)zb * (SEGS * 256) + t;
    union { __half2 h; unsigned int u; } pk;
    pk.h = __halves2half2(__float2half(slope), __float2half(icpt));
    rowp[0] = pk.u;
    for (int s = 1; s < SEGS; ++s) {
        float h = hL[ordS[s - 1]][tid];
        slope = fmaf(dwS[s - 1], h, slope);
        icpt  = fmaf(dbS[s - 1], h, icpt);
        pk.h = __halves2half2(__float2half(slope), __float2half(icpt));
        rowp[(size_t)s * 256] = pk.u;
    }
}

static __device__ __forceinline__ float rcomb(unsigned int v, float r) {
    union { unsigned int u; __half2 h; } cv; cv.u = v;
    return fmaf(r, __low2float(cv.h), __high2float(cv.h));
}

__global__ __launch_bounds__(256, 4) void k_main(const float* __restrict__ geom,
                                                 const float* __restrict__ mask,
                                                 const unsigned int* __restrict__ PC,
                                                 float* __restrict__ out) {
    int wv   = threadIdx.x >> 6;
    int lane = threadIdx.x & 63;
    int gw   = blockIdx.x * 4 + wv;     // 4 waves of a block share za
    int chunk = gw & (CW - 1);
    int za    = gw >> 5;                // z*160 + a
    int z     = za / NA;

    __shared__ float sAcc[4][64];

    bool l0 = lane < 16;
    int  u = 0, part = 0;
    if (!l0) { int lu = lane - 16; u = lu / 3; part = lu - u * 3; }
    float zft = l0 ? 1.4142135623730951f : 2.0f;   // zero-radius norm ratio
    float thrv = dg_thr[lane];

    const float is30 = 0.18257418583505536f;  // 1/sqrt(30)
    const float is10 = 0.31622776601683794f;  // 1/sqrt(10)
    const float c1sh = 0.4886025119029199f;
    const float c21 = 1.0925484305920792f, c22 = 0.31539156525252005f, c23 = 0.5462742152960396f;

    // ---- geometry / segment for all PPW pairs ----
    int b0 = chunk * PPW;
    float rr[PPW], nxa[PPW], nya[PPW], nza[PPW], zfa[PPW];
    unsigned int rowo[PPW];
    #pragma unroll
    for (int it = 0; it < PPW; ++it) {
        const float* g = geom + ((size_t)za * NB + b0 + it) * 3;
        float gx = g[0], gy = g[1], gz = g[2];
        float r = sqrtf(gx * gx + gy * gy + gz * gz);
        bool zr = (r == 0.0f);
        float inv = zr ? 1.0f : (1.0f / r);
        nxa[it] = gx * inv; nya[it] = gy * inv; nza[it] = gz * inv;
        rr[it] = r;
        zfa[it] = zr ? zft : 1.0f;
        unsigned long long bm = __ballot(thrv < r);
        int s = __popcll(bm);
        rowo[it] = ((unsigned)(z * NB + b0 + it) * SEGS + (unsigned)s) * 256u
                 + (unsigned)(lane * 4);
    }

    float acc0 = 0.0f, acc1 = 0.0f, acc2 = 0.0f;

    // ---- software pipeline: one dwordx4 per lane per pair ----
    uint4 tb[2];
    tb[0] = *(const uint4*)(PC + rowo[0]);

    #pragma unroll
    for (int it = 0; it < PPW; ++it) {
        if (it + 1 < PPW) tb[(it + 1) & 1] = *(const uint4*)(PC + rowo[it + 1]);
        uint4 tt = tb[it & 1];
        float r = rr[it];
        float T0 = rcomb(tt.x, r);
        float T1 = rcomb(tt.y, r);
        float T2 = rcomb(tt.z, r);
        float T3 = rcomb(tt.w, r);

        float nx = nxa[it], ny = nya[it], nz = nza[it];
        float Y1_0 = c1sh * ny, Y1_1 = c1sh * nz, Y1_2 = c1sh * nx;
        float zf = zfa[it];

        if (l0) {
            // out(l0,u) partial: T0 + Y1 . T1vec
            float sl0 = T0;
            sl0 = fmaf(Y1_0, T1, sl0);
            sl0 = fmaf(Y1_1, T2, sl0);
            sl0 = fmaf(Y1_2, T3, sl0);
            acc0 = fmaf(sl0, zf, acc0);
        } else if (part == 0) {
            // T0 (C) + T1vec (D) terms of s_xyz
            float px = fmaf(Y1_0, T0, T1);
            float py = fmaf(Y1_1, T0, T2);
            float pz = fmaf(Y1_2, T0, T3);
            acc0 = fmaf(px, zf, acc0);
            acc1 = fmaf(py, zf, acc1);
            acc2 = fmaf(pz, zf, acc2);
        } else if (part == 1) {
            // T2vec (E) cross terms
            float px = fmaf(Y1_2, T1, -Y1_1 * T2);
            float py = fmaf(Y1_0, T2, -Y1_2 * T0);
            float pz = fmaf(Y1_1, T0, -Y1_0 * T1);
            acc0 = fmaf(px, zf, acc0);
            acc1 = fmaf(py, zf, acc1);
            acc2 = fmaf(pz, zf, acc2);
        } else {
            // T3vec (F) l=2 terms
            float Y2_0 = c21 * nx * ny;
            float Y2_1 = c21 * ny * nz;
            float Y2_2 = c22 * fmaf(3.0f, nz * nz, -1.0f);
            float Y2_3 = c21 * nx * nz;
            float Y2_4 = c23 * (nx * nx - ny * ny);
            float za_ = is10 * Y2_0, zb_ = is10 * Y2_1, zc_ = is10 * Y2_3;
            float zd_ = is30 * Y2_2, ze_ = is10 * Y2_4;
            float px = fmaf(-(zd_ + ze_), T0, fmaf(zb_, T1, za_ * T2));
            float py = fmaf(zb_, T0, fmaf(2.0f * zd_, T1, zc_ * T2));
            float pz = fmaf(za_, T0, fmaf(zc_, T1, (ze_ - zd_) * T2));
            acc0 = fmaf(px, zf, acc0);
            acc1 = fmaf(py, zf, acc1);
            acc2 = fmaf(pz, zf, acc2);
        }
    }

    // ---- combine the 3 l1 parts (lanes 16+3u+{0,1,2}) ----
    float ax = acc0 + __shfl_down(acc0, 1) + __shfl_down(acc0, 2);
    float ay = acc1 + __shfl_down(acc1, 1) + __shfl_down(acc1, 2);
    float az = acc2 + __shfl_down(acc2, 1) + __shfl_down(acc2, 2);
    if (l0) {
        sAcc[wv][lane] = acc0;
    } else if (part == 0) {
        int ob = 16 + u * 3;
        sAcc[wv][ob]     = ax;
        sAcc[wv][ob + 1] = ay;
        sAcc[wv][ob + 2] = az;
    }
    __syncthreads();
    if (threadIdx.x < 64) {
        float sum = sAcc[0][threadIdx.x] + sAcc[1][threadIdx.x]
                  + sAcc[2][threadIdx.x] + sAcc[3][threadIdx.x];
        sum *= mask[za];
        atomicAdd(&out[(size_t)za * 64 + threadIdx.x], sum);
    }
}

extern "C" void kernel_launch(void* const* d_in, const int* in_sizes, int n_in,
                              void* d_out, int out_size, void* d_ws, size_t ws_size,
                              hipStream_t stream) {
    (void)in_sizes; (void)n_in; (void)ws_size; (void)out_size;
    const float* feat = (const float*)d_in[0];
    const float* geom = (const float*)d_in[1];
    const float* mask = (const float*)d_in[2];
    const float* W1   = (const float*)d_in[3];
    const float* b1   = (const float*)d_in[4];
    const float* W2   = (const float*)d_in[5];
    const float* b2   = (const float*)d_in[6];
    float* out = (float*)d_out;
    float* ws  = (float*)d_ws;                 // PC | W2G | B2T (~22.4 MB)
    unsigned int* PC = (unsigned int*)d_ws;

    k_w2g<<<337, 256, 0, stream>>>(W1, b1, W2, b2, ws, out);  // gather + order + zero
    k_pc2<<<640, 128, 0, stream>>>(feat, ws, PC);
    k_main<<<2 * NA * CW / 4, 256, 0, stream>>>(geom, mask, PC, out);
}

// Round 3
// 99.298 us; speedup vs baseline: 1.3088x; 1.1243x over previous
//
#include <hip/hip_runtime.h>
#include <hip/hip_fp16.h>
#include <math.h>

#define NPATH 1536
#define SEGS  65        // 0..64 active-channel counts
#define NB    160
#define NA    160
#define CW    32        // chunks (waves) per (z,a)
#define PPW   5         // pairs per wave = NB/CW

// d_ws layout:
//   [0, 21.3MB)  PC[zb][seg][256 u32]  — packed {fp16 slope | fp16 icpt}
//   [21.3MB, +2.1MB) SWB[t][seg][16 v]{sw,sb} float2 — feature-independent
//                    per-slot segment table (threshold-prefix over channels)
// slot t = lane*4 + j (k_main reads uint4 per lane):
//   lane  0..15 (l0 task u=lane): j0 = A(u)->T0 ; j1..3 = B(u,xyz)->T1c
//   lane 16..63 (l1 task u=(lane-16)/3, part=(lane-16)%3):
//     part0: j0 = C(u)->T0 ; j1..3 = D(u,xyz)->T1c
//     part1: j0..2 = E(u,xyz)->T2c ; j3 pad
//     part2: j0..2 = F(u,xyz)->T3c ; j3 pad
#define PC_U32S   (320 * SEGS * 256)            // 5,324,800 u32
#define SWB_OFF   PC_U32S                        // float offset into ws

__device__ float dg_thr[64];

#define SCL_A 0.17677669529663687f
#define SCL_B 0.6266570686577502f
#define SCL_C 0.2558286876965162f
#define SCL_D 0.125f
#define SCL_E 0.3133285343288751f
#define SCL_F 0.7674950309598664f

// slot t -> (path base, path stride, feature component, folded scale).
// comp == -1 -> feature f[v]; else f[16 + 3v + comp]. Pad slots: scl = 0.
static __device__ __forceinline__ void slot_map(int t, int& pbase, int& pstr,
                                                int& comp, float& scl) {
    int lane4 = t >> 2, j = t & 3;
    pbase = 0; pstr = 1; comp = -1; scl = 0.0f;
    if (lane4 < 16) {
        if (j == 0) { pbase = lane4 * 16;       scl = SCL_A; }
        else        { pbase = 256 + lane4 * 16; comp = j - 1; scl = SCL_B; }
    } else {
        int lu = lane4 - 16, u = lu / 3, part = lu - u * 3;
        if (part == 0) {
            if (j == 0) { pbase = 512 + u * 16;                       scl = SCL_C; }
            else        { pbase = 768 + u * 48; pstr = 3; comp = j - 1; scl = SCL_D; }
        } else if (part == 1) {
            if (j < 3)  { pbase = 768 + u * 48 + 1; pstr = 3; comp = j; scl = SCL_E; }
        } else {
            if (j < 3)  { pbase = 768 + u * 48 + 2; pstr = 3; comp = j; scl = SCL_F; }
        }
    }
}

// blocks 0..255: one per slot t — load the 16x64 W2 tile, build the 65-segment
// SW/SB prefix (feature-independent), write SWB[t]. blocks 256..415: zero d_out.
__global__ __launch_bounds__(128) void k_sw(const float* __restrict__ W1,
                                            const float* __restrict__ b1,
                                            const float* __restrict__ W2,
                                            const float* __restrict__ b2,
                                            float* __restrict__ ws,
                                            float* __restrict__ out) {
    int bid = blockIdx.x, tid = threadIdx.x;
    if (bid >= 256) {                       // 160 blocks x 128 = 20480 floats
        out[(bid - 256) * 128 + tid] = 0.0f;
        return;
    }
    int t = bid;

    __shared__ float tvS[64], iwS[64], ibS[64], dwS[64], dbS[64], b2S[16];
    __shared__ int   ordS[64];
    __shared__ float W2t[16][65];           // pad 65: stride-65 reads hit 16 banks

    if (tid < 64) {
        float w = W1[tid], bb = b1[tid];
        tvS[tid] = (w != 0.0f) ? (-bb / w) : __builtin_inff();
    }
    __syncthreads();
    if (tid < 64) {
        float mine = tvS[tid];
        int rank = 0;
        for (int j2 = 0; j2 < 64; ++j2) {
            float o = tvS[j2];
            rank += (o < mine || (o == mine && j2 < tid)) ? 1 : 0;
        }
        float w = W1[tid], bb = b1[tid];
        // seg-0 active set: {w<0} u {w==0 && b>0}
        iwS[tid] = (w < 0.0f) ? w : 0.0f;
        ibS[tid] = (w < 0.0f) ? bb : ((w == 0.0f && bb > 0.0f) ? bb : 0.0f);
        // step s flips the channel with rank s-1: w>0 adds, w<0 removes
        ordS[rank] = tid;
        dwS[rank]  = fabsf(w);
        dbS[rank]  = (w > 0.0f) ? bb : ((w < 0.0f) ? -bb : 0.0f);
        if (t == 0) dg_thr[tid] = mine;
    }

    int pbase, pstr, comp; float scl;
    slot_map(t, pbase, pstr, comp, scl);
    (void)comp;

    int c = tid & 63, vh = tid >> 6;        // 2 waves x 8 v each
    #pragma unroll
    for (int i = 0; i < 8; ++i) {
        int v = vh * 8 + i;
        W2t[v][c] = scl * W2[(size_t)c * NPATH + pbase + v * pstr];
    }
    if (tid < 16) b2S[tid] = scl * b2[pbase + tid * pstr];
    __syncthreads();

    if (tid < 16) {
        int v = tid;
        float sw = 0.0f, sb = 0.0f;
        #pragma unroll 4
        for (int cc = 0; cc < 64; ++cc) {
            float w2 = W2t[v][cc];
            sw = fmaf(iwS[cc], w2, sw);
            sb = fmaf(ibS[cc], w2, sb);
        }
        sb += b2S[v];
        float2* rp = (float2*)(ws + SWB_OFF + (size_t)t * SEGS * 32) + v;
        *rp = make_float2(sw, sb);
        for (int s = 1; s < SEGS; ++s) {
            int cs = ordS[s - 1];
            float w2 = W2t[v][cs];
            sw = fmaf(dwS[s - 1], w2, sw);
            sb = fmaf(dbS[s - 1], w2, sb);
            rp += 16;
            *rp = make_float2(sw, sb);
        }
    }
}

// Tiny batched GEMM: PC[zb][s][T] = pack(sum_v f*SW, sum_v f*SB).
// grid = 16 t-groups x 16 zb-tiles; SW rows in registers, 20-zb reuse;
// features staged (permuted by comp) once per block in LDS.
__global__ __launch_bounds__(256) void k_pc3(const float* __restrict__ feat,
                                             const float* __restrict__ ws,
                                             unsigned int* __restrict__ PC) {
    int tg = blockIdx.x & 15, zt = blockIdx.x >> 4;
    int zb0 = zt * 20;

    __shared__ __align__(16) float fS[20][64];   // [zb][ct*16 + v]
    #pragma unroll
    for (int i = 0; i < 5; ++i) {
        int idx = threadIdx.x + i * 256;
        int row = idx >> 6, fi = idx & 63;
        float val = feat[(size_t)(zb0 + row) * 64 + fi];
        int dest;
        if (fi < 16) dest = fi;
        else { int q = (fi - 16) / 3, c3 = (fi - 16) - 3 * q; dest = (c3 + 1) * 16 + q; }
        fS[row][dest] = val;
    }
    __syncthreads();

    int t = threadIdx.x & 15, sgrp = threadIdx.x >> 4;
    int T = tg * 16 + t;
    int pbase, pstr, comp; float scl;
    slot_map(T, pbase, pstr, comp, scl);
    (void)pbase; (void)pstr; (void)scl;
    const float* fb = &fS[0][(comp + 1) * 16];

    for (int k = 0; k < 5; ++k) {
        int s = sgrp + 16 * k;               // strided s: stores stay coalesced
        if (s >= SEGS) break;
        const float4* rp = (const float4*)(ws + SWB_OFF + ((size_t)T * SEGS + s) * 32);
        float4 q0 = rp[0], q1 = rp[1], q2 = rp[2], q3 = rp[3];
        float4 q4 = rp[4], q5 = rp[5], q6 = rp[6], q7 = rp[7];
        unsigned int* op = PC + (size_t)zb0 * (SEGS * 256) + (size_t)s * 256 + T;
        #pragma unroll 4
        for (int zb = 0; zb < 20; ++zb) {
            const float4* fp = (const float4*)(fb + zb * 64);
            float4 f0 = fp[0], f1 = fp[1], f2 = fp[2], f3 = fp[3];
            float sw = q0.x * f0.x,          sb = q0.y * f0.x;
            sw = fmaf(q0.z, f0.y, sw);  sb = fmaf(q0.w, f0.y, sb);
            sw = fmaf(q1.x, f0.z, sw);  sb = fmaf(q1.y, f0.z, sb);
            sw = fmaf(q1.z, f0.w, sw);  sb = fmaf(q1.w, f0.w, sb);
            sw = fmaf(q2.x, f1.x, sw);  sb = fmaf(q2.y, f1.x, sb);
            sw = fmaf(q2.z, f1.y, sw);  sb = fmaf(q2.w, f1.y, sb);
            sw = fmaf(q3.x, f1.z, sw);  sb = fmaf(q3.y, f1.z, sb);
            sw = fmaf(q3.z, f1.w, sw);  sb = fmaf(q3.w, f1.w, sb);
            sw = fmaf(q4.x, f2.x, sw);  sb = fmaf(q4.y, f2.x, sb);
            sw = fmaf(q4.z, f2.y, sw);  sb = fmaf(q4.w, f2.y, sb);
            sw = fmaf(q5.x, f2.z, sw);  sb = fmaf(q5.y, f2.z, sb);
            sw = fmaf(q5.z, f2.w, sw);  sb = fmaf(q5.w, f2.w, sb);
            sw = fmaf(q6.x, f3.x, sw);  sb = fmaf(q6.y, f3.x, sb);
            sw = fmaf(q6.z, f3.y, sw);  sb = fmaf(q6.w, f3.y, sb);
            sw = fmaf(q7.x, f3.z, sw);  sb = fmaf(q7.y, f3.z, sb);
            sw = fmaf(q7.z, f3.w, sw);  sb = fmaf(q7.w, f3.w, sb);
            union { __half2 h; unsigned int u; } pk;
            pk.h = __halves2half2(__float2half(sw), __float2half(sb));
            op[(size_t)zb * (SEGS * 256)] = pk.u;
        }
    }
}

static __device__ __forceinline__ float rcomb(unsigned int v, float r) {
    union { unsigned int u; __half2 h; } cv; cv.u = v;
    return fmaf(r, __low2float(cv.h), __high2float(cv.h));
}

__global__ __launch_bounds__(256, 4) void k_main(const float* __restrict__ geom,
                                                 const float* __restrict__ mask,
                                                 const unsigned int* __restrict__ PC,
                                                 float* __restrict__ out) {
    int wv   = threadIdx.x >> 6;
    int lane = threadIdx.x & 63;
    int gw   = blockIdx.x * 4 + wv;     // 4 waves of a block share za
    int chunk = gw & (CW - 1);
    int za    = gw >> 5;                // z*160 + a
    int z     = za / NA;

    __shared__ float sAcc[4][64];

    bool l0 = lane < 16;
    int  u = 0, part = 0;
    if (!l0) { int lu = lane - 16; u = lu / 3; part = lu - u * 3; }
    float zft = l0 ? 1.4142135623730951f : 2.0f;   // zero-radius norm ratio
    float thrv = dg_thr[lane];

    const float is30 = 0.18257418583505536f;  // 1/sqrt(30)
    const float is10 = 0.31622776601683794f;  // 1/sqrt(10)
    const float c1sh = 0.4886025119029199f;
    const float c21 = 1.0925484305920792f, c22 = 0.31539156525252005f, c23 = 0.5462742152960396f;

    // ---- geometry / segment for all PPW pairs ----
    int b0 = chunk * PPW;
    float rr[PPW], nxa[PPW], nya[PPW], nza[PPW], zfa[PPW];
    unsigned int rowo[PPW];
    #pragma unroll
    for (int it = 0; it < PPW; ++it) {
        const float* g = geom + ((size_t)za * NB + b0 + it) * 3;
        float gx = g[0], gy = g[1], gz = g[2];
        float r = sqrtf(gx * gx + gy * gy + gz * gz);
        bool zr = (r == 0.0f);
        float inv = zr ? 1.0f : (1.0f / r);
        nxa[it] = gx * inv; nya[it] = gy * inv; nza[it] = gz * inv;
        rr[it] = r;
        zfa[it] = zr ? zft : 1.0f;
        unsigned long long bm = __ballot(thrv < r);
        int s = __popcll(bm);
        rowo[it] = ((unsigned)(z * NB + b0 + it) * SEGS + (unsigned)s) * 256u
                 + (unsigned)(lane * 4);
    }

    float acc0 = 0.0f, acc1 = 0.0f, acc2 = 0.0f;

    // ---- software pipeline: one dwordx4 per lane per pair ----
    uint4 tb[2];
    tb[0] = *(const uint4*)(PC + rowo[0]);

    #pragma unroll
    for (int it = 0; it < PPW; ++it) {
        if (it + 1 < PPW) tb[(it + 1) & 1] = *(const uint4*)(PC + rowo[it + 1]);
        uint4 tt = tb[it & 1];
        float r = rr[it];
        float T0 = rcomb(tt.x, r);
        float T1 = rcomb(tt.y, r);
        float T2 = rcomb(tt.z, r);
        float T3 = rcomb(tt.w, r);

        float nx = nxa[it], ny = nya[it], nz = nza[it];
        float Y1_0 = c1sh * ny, Y1_1 = c1sh * nz, Y1_2 = c1sh * nx;
        float zf = zfa[it];

        if (l0) {
            // out(l0,u) partial: T0 + Y1 . T1vec
            float sl0 = T0;
            sl0 = fmaf(Y1_0, T1, sl0);
            sl0 = fmaf(Y1_1, T2, sl0);
            sl0 = fmaf(Y1_2, T3, sl0);
            acc0 = fmaf(sl0, zf, acc0);
        } else if (part == 0) {
            // T0 (C) + T1vec (D) terms of s_xyz
            float px = fmaf(Y1_0, T0, T1);
            float py = fmaf(Y1_1, T0, T2);
            float pz = fmaf(Y1_2, T0, T3);
            acc0 = fmaf(px, zf, acc0);
            acc1 = fmaf(py, zf, acc1);
            acc2 = fmaf(pz, zf, acc2);
        } else if (part == 1) {
            // T2vec (E) cross terms
            float px = fmaf(Y1_2, T1, -Y1_1 * T2);
            float py = fmaf(Y1_0, T2, -Y1_2 * T0);
            float pz = fmaf(Y1_1, T0, -Y1_0 * T1);
            acc0 = fmaf(px, zf, acc0);
            acc1 = fmaf(py, zf, acc1);
            acc2 = fmaf(pz, zf, acc2);
        } else {
            // T3vec (F) l=2 terms
            float Y2_0 = c21 * nx * ny;
            float Y2_1 = c21 * ny * nz;
            float Y2_2 = c22 * fmaf(3.0f, nz * nz, -1.0f);
            float Y2_3 = c21 * nx * nz;
            float Y2_4 = c23 * (nx * nx - ny * ny);
            float za_ = is10 * Y2_0, zb_ = is10 * Y2_1, zc_ = is10 * Y2_3;
            float zd_ = is30 * Y2_2, ze_ = is10 * Y2_4;
            float px = fmaf(-(zd_ + ze_), T0, fmaf(zb_, T1, za_ * T2));
            float py = fmaf(zb_, T0, fmaf(2.0f * zd_, T1, zc_ * T2));
            float pz = fmaf(za_, T0, fmaf(zc_, T1, (ze_ - zd_) * T2));
            acc0 = fmaf(px, zf, acc0);
            acc1 = fmaf(py, zf, acc1);
            acc2 = fmaf(pz, zf, acc2);
        }
    }

    // ---- combine the 3 l1 parts (lanes 16+3u+{0,1,2}) ----
    float ax = acc0 + __shfl_down(acc0, 1) + __shfl_down(acc0, 2);
    float ay = acc1 + __shfl_down(acc1, 1) + __shfl_down(acc1, 2);
    float az = acc2 + __shfl_down(acc2, 1) + __shfl_down(acc2, 2);
    if (l0) {
        sAcc[wv][lane] = acc0;
    } else if (part == 0) {
        int ob = 16 + u * 3;
        sAcc[wv][ob]     = ax;
        sAcc[wv][ob + 1] = ay;
        sAcc[wv][ob + 2] = az;
    }
    __syncthreads();
    if (threadIdx.x < 64) {
        float sum = sAcc[0][threadIdx.x] + sAcc[1][threadIdx.x]
                  + sAcc[2][threadIdx.x] + sAcc[3][threadIdx.x];
        sum *= mask[za];
        atomicAdd(&out[(size_t)za * 64 + threadIdx.x], sum);
    }
}

extern "C" void kernel_launch(void* const* d_in, const int* in_sizes, int n_in,
                              void* d_out, int out_size, void* d_ws, size_t ws_size,
                              hipStream_t stream) {
    (void)in_sizes; (void)n_in; (void)ws_size; (void)out_size;
    const float* feat = (const float*)d_in[0];
    const float* geom = (const float*)d_in[1];
    const float* mask = (const float*)d_in[2];
    const float* W1   = (const float*)d_in[3];
    const float* b1   = (const float*)d_in[4];
    const float* W2   = (const float*)d_in[5];
    const float* b2   = (const float*)d_in[6];
    float* out = (float*)d_out;
    float* ws  = (float*)d_ws;                 // PC (21.3MB) | SWB (2.1MB)
    unsigned int* PC = (unsigned int*)d_ws;

    k_sw  <<<416, 128, 0, stream>>>(W1, b1, W2, b2, ws, out);  // 256 table + 160 zero
    k_pc3 <<<256, 256, 0, stream>>>(feat, ws, PC);
    k_main<<<2 * NA * CW / 4, 256, 0, stream>>>(geom, mask, PC, out);
}

// Round 4
// 96.106 us; speedup vs baseline: 1.3523x; 1.0332x over previous
//
#include <hip/hip_runtime.h>
#include <hip/hip_fp16.h>
#include <math.h>

#define NPATH 1536
#define SEGS  65        // 0..64 active-channel counts
#define NB    160
#define NA    160
#define CW    32        // chunks (waves) per (z,a)
#define PPW   5         // pairs per wave = NB/CW

// d_ws layout:
//   [0, 21.3MB)  PC[zb][seg][256 u32]  — packed {fp16 slope | fp16 icpt}
//   [21.3MB, +2.1MB) SWB[t][seg][16 v]{sw,sb} float2 — feature-independent
//                    per-slot segment table (threshold-prefix over channels)
// slot t = lane*4 + j (k_main reads uint4 per lane):
//   lane  0..15 (l0 task u=lane): j0 = A(u)->T0 ; j1..3 = B(u,xyz)->T1c
//   lane 16..63 (l1 task u=(lane-16)/3, part=(lane-16)%3):
//     part0: j0 = C(u)->T0 ; j1..3 = D(u,xyz)->T1c
//     part1: j0..2 = E(u,xyz)->T2c ; j3 pad
//     part2: j0..2 = F(u,xyz)->T3c ; j3 pad
#define PC_U32S   (320 * SEGS * 256)            // 5,324,800 u32
#define SWB_OFF   PC_U32S                        // float offset into ws

__device__ float dg_thr[64];

#define SCL_A 0.17677669529663687f
#define SCL_B 0.6266570686577502f
#define SCL_C 0.2558286876965162f
#define SCL_D 0.125f
#define SCL_E 0.3133285343288751f
#define SCL_F 0.7674950309598664f

// slot t -> (path base, path stride, feature component, folded scale).
// comp == -1 -> feature f[v]; else f[16 + 3v + comp]. Pad slots: scl = 0.
static __device__ __forceinline__ void slot_map(int t, int& pbase, int& pstr,
                                                int& comp, float& scl) {
    int lane4 = t >> 2, j = t & 3;
    pbase = 0; pstr = 1; comp = -1; scl = 0.0f;
    if (lane4 < 16) {
        if (j == 0) { pbase = lane4 * 16;       scl = SCL_A; }
        else        { pbase = 256 + lane4 * 16; comp = j - 1; scl = SCL_B; }
    } else {
        int lu = lane4 - 16, u = lu / 3, part = lu - u * 3;
        if (part == 0) {
            if (j == 0) { pbase = 512 + u * 16;                       scl = SCL_C; }
            else        { pbase = 768 + u * 48; pstr = 3; comp = j - 1; scl = SCL_D; }
        } else if (part == 1) {
            if (j < 3)  { pbase = 768 + u * 48 + 1; pstr = 3; comp = j; scl = SCL_E; }
        } else {
            if (j < 3)  { pbase = 768 + u * 48 + 2; pstr = 3; comp = j; scl = SCL_F; }
        }
    }
}

// blocks 0..255: one per slot t. All 256 threads busy: thread = (v, s-quad);
// direct masked base sum at s0 (branchless sel on precomputed rank) + <=4-step
// local prefix. blocks 256..335: zero d_out.
__global__ __launch_bounds__(256) void k_sw(const float* __restrict__ W1,
                                            const float* __restrict__ b1,
                                            const float* __restrict__ W2,
                                            const float* __restrict__ b2,
                                            float* __restrict__ ws,
                                            float* __restrict__ out) {
    int bid = blockIdx.x, tid = threadIdx.x;
    if (bid >= 256) {                       // 80 blocks x 256 = 20480 floats
        out[(bid - 256) * 256 + tid] = 0.0f;
        return;
    }
    int t = bid;

    __shared__ float  tvS[64];
    __shared__ float4 chS[64];              // {wPos, wNeg, bSel, bUnsel}
    __shared__ int    rkS[64];
    __shared__ int    ordS[64];
    __shared__ float  dwS[64], dbS[64], b2S[16];
    __shared__ float  W2t[16][65];          // pad 65

    if (tid < 64) {
        float w = W1[tid], bb = b1[tid];
        tvS[tid] = (w != 0.0f) ? (-bb / w) : __builtin_inff();
    }
    __syncthreads();
    if (tid < 64) {
        float mine = tvS[tid];
        int rank = 0;
        for (int j2 = 0; j2 < 64; ++j2) {
            float o = tvS[j2];
            rank += (o < mine || (o == mine && j2 < tid)) ? 1 : 0;
        }
        float w = W1[tid], bb = b1[tid];
        // sel (= rank < s): channel is in the "threshold passed" set.
        //   w>0: active iff sel;  w<0: active iff !sel;  w==0: active iff b>0
        //   (w==0 has rank >= #finite >= s for all readable rows -> !sel).
        chS[tid] = make_float4((w > 0.0f) ? w : 0.0f,
                               (w < 0.0f) ? w : 0.0f,
                               (w > 0.0f) ? bb : 0.0f,
                               (w < 0.0f) ? bb : ((w == 0.0f && bb > 0.0f) ? bb : 0.0f));
        rkS[tid] = rank;
        // step s -> s+1 flips the channel with rank s: w>0 adds, w<0 removes
        ordS[rank] = tid;
        dwS[rank]  = fabsf(w);
        dbS[rank]  = (w > 0.0f) ? bb : ((w < 0.0f) ? -bb : 0.0f);
        if (t == 0) dg_thr[tid] = mine;
    }

    int pbase, pstr, comp; float scl;
    slot_map(t, pbase, pstr, comp, scl);
    (void)comp;
    int c = tid & 63, vh = tid >> 6;        // 4 groups x 4 v each
    #pragma unroll
    for (int i = 0; i < 4; ++i) {
        int v = vh * 4 + i;
        W2t[v][c] = scl * W2[(size_t)c * NPATH + pbase + v * pstr];
    }
    if (tid < 16) b2S[tid] = scl * b2[pbase + tid * pstr];
    __syncthreads();

    int v = tid & 15, sq = tid >> 4;        // 16 v x 16 s-quads
    int s0 = sq * 4;
    float sw = 0.0f, sb = 0.0f;
    #pragma unroll 8
    for (int cc = 0; cc < 64; ++cc) {
        float  w2 = W2t[v][cc];
        float4 ch = chS[cc];                // broadcast
        bool sel = rkS[cc] < s0;
        sw = fmaf(sel ? ch.x : ch.y, w2, sw);
        sb = fmaf(sel ? ch.z : ch.w, w2, sb);
    }
    sb += b2S[v];

    int ns = (sq == 15) ? 5 : 4;            // sq 15 also writes s=64
    float2* rp = (float2*)(ws + SWB_OFF + ((size_t)t * SEGS + s0) * 32) + v;
    for (int i = 0; i < ns; ++i) {
        rp[(size_t)i * 16] = make_float2(sw, sb);
        if (i + 1 < ns) {
            int s = s0 + i;
            float w2s = W2t[v][ordS[s]];
            sw = fmaf(dwS[s], w2s, sw);
            sb = fmaf(dbS[s], w2s, sb);
        }
    }
}

// Tiny batched GEMM: PC[zb][s][T] = pack(sum_v f*SW, sum_v f*SB).
// grid = 16 t-groups x 32 zb-tiles (tile=10) -> 2 blocks/CU for latency hiding;
// SWB rows (2.1MB) are per-XCD L2-resident so the re-read is cheap.
__global__ __launch_bounds__(256) void k_pc3(const float* __restrict__ feat,
                                             const float* __restrict__ ws,
                                             unsigned int* __restrict__ PC) {
    int tg = blockIdx.x & 15, zt = blockIdx.x >> 4;
    int zb0 = zt * 10;

    __shared__ __align__(16) float fS[10][64];   // [zb][ct*16 + v]
    #pragma unroll
    for (int i = 0; i < 3; ++i) {
        int idx = threadIdx.x + i * 256;
        if (idx < 640) {
            int row = idx >> 6, fi = idx & 63;
            float val = feat[(size_t)(zb0 + row) * 64 + fi];
            int dest;
            if (fi < 16) dest = fi;
            else { int q = (fi - 16) / 3, c3 = (fi - 16) - 3 * q; dest = (c3 + 1) * 16 + q; }
            fS[row][dest] = val;
        }
    }
    __syncthreads();

    int t = threadIdx.x & 15, sgrp = threadIdx.x >> 4;
    int T = tg * 16 + t;
    int pbase, pstr, comp; float scl;
    slot_map(T, pbase, pstr, comp, scl);
    (void)pbase; (void)pstr; (void)scl;
    const float* fb = &fS[0][(comp + 1) * 16];

    for (int k = 0; k < 5; ++k) {
        int s = sgrp + 16 * k;               // strided s: stores stay coalesced
        if (s >= SEGS) break;
        const float4* rp = (const float4*)(ws + SWB_OFF + ((size_t)T * SEGS + s) * 32);
        float4 q0 = rp[0], q1 = rp[1], q2 = rp[2], q3 = rp[3];
        float4 q4 = rp[4], q5 = rp[5], q6 = rp[6], q7 = rp[7];
        unsigned int* op = PC + (size_t)zb0 * (SEGS * 256) + (size_t)s * 256 + T;
        #pragma unroll 2
        for (int zb = 0; zb < 10; ++zb) {
            const float4* fp = (const float4*)(fb + zb * 64);
            float4 f0 = fp[0], f1 = fp[1], f2 = fp[2], f3 = fp[3];
            float sw = q0.x * f0.x,          sb = q0.y * f0.x;
            sw = fmaf(q0.z, f0.y, sw);  sb = fmaf(q0.w, f0.y, sb);
            sw = fmaf(q1.x, f0.z, sw);  sb = fmaf(q1.y, f0.z, sb);
            sw = fmaf(q1.z, f0.w, sw);  sb = fmaf(q1.w, f0.w, sb);
            sw = fmaf(q2.x, f1.x, sw);  sb = fmaf(q2.y, f1.x, sb);
            sw = fmaf(q2.z, f1.y, sw);  sb = fmaf(q2.w, f1.y, sb);
            sw = fmaf(q3.x, f1.z, sw);  sb = fmaf(q3.y, f1.z, sb);
            sw = fmaf(q3.z, f1.w, sw);  sb = fmaf(q3.w, f1.w, sb);
            sw = fmaf(q4.x, f2.x, sw);  sb = fmaf(q4.y, f2.x, sb);
            sw = fmaf(q4.z, f2.y, sw);  sb = fmaf(q4.w, f2.y, sb);
            sw = fmaf(q5.x, f2.z, sw);  sb = fmaf(q5.y, f2.z, sb);
            sw = fmaf(q5.z, f2.w, sw);  sb = fmaf(q5.w, f2.w, sb);
            sw = fmaf(q6.x, f3.x, sw);  sb = fmaf(q6.y, f3.x, sb);
            sw = fmaf(q6.z, f3.y, sw);  sb = fmaf(q6.w, f3.y, sb);
            sw = fmaf(q7.x, f3.z, sw);  sb = fmaf(q7.y, f3.z, sb);
            sw = fmaf(q7.z, f3.w, sw);  sb = fmaf(q7.w, f3.w, sb);
            union { __half2 h; unsigned int u; } pk;
            pk.h = __halves2half2(__float2half(sw), __float2half(sb));
            op[(size_t)zb * (SEGS * 256)] = pk.u;
        }
    }
}

static __device__ __forceinline__ float rcomb(unsigned int v, float r) {
    union { unsigned int u; __half2 h; } cv; cv.u = v;
    return fmaf(r, __low2float(cv.h), __high2float(cv.h));
}

__global__ __launch_bounds__(256, 4) void k_main(const float* __restrict__ geom,
                                                 const float* __restrict__ mask,
                                                 const unsigned int* __restrict__ PC,
                                                 float* __restrict__ out) {
    int wv   = threadIdx.x >> 6;
    int lane = threadIdx.x & 63;
    int gw   = blockIdx.x * 4 + wv;     // 4 waves of a block share za
    int chunk = gw & (CW - 1);
    int za    = gw >> 5;                // z*160 + a
    int z     = za / NA;

    __shared__ float sAcc[4][64];

    bool l0 = lane < 16;
    int  u = 0, part = 0;
    if (!l0) { int lu = lane - 16; u = lu / 3; part = lu - u * 3; }
    float zft = l0 ? 1.4142135623730951f : 2.0f;   // zero-radius norm ratio
    float thrv = dg_thr[lane];

    const float is30 = 0.18257418583505536f;  // 1/sqrt(30)
    const float is10 = 0.31622776601683794f;  // 1/sqrt(10)
    const float c1sh = 0.4886025119029199f;
    const float c21 = 1.0925484305920792f, c22 = 0.31539156525252005f, c23 = 0.5462742152960396f;

    // ---- geometry / segment for all PPW pairs ----
    int b0 = chunk * PPW;
    float rr[PPW], nxa[PPW], nya[PPW], nza[PPW], zfa[PPW];
    unsigned int rowo[PPW];
    #pragma unroll
    for (int it = 0; it < PPW; ++it) {
        const float* g = geom + ((size_t)za * NB + b0 + it) * 3;
        float gx = g[0], gy = g[1], gz = g[2];
        float r = sqrtf(gx * gx + gy * gy + gz * gz);
        bool zr = (r == 0.0f);
        float inv = zr ? 1.0f : (1.0f / r);
        nxa[it] = gx * inv; nya[it] = gy * inv; nza[it] = gz * inv;
        rr[it] = r;
        zfa[it] = zr ? zft : 1.0f;
        unsigned long long bm = __ballot(thrv < r);
        int s = __popcll(bm);
        rowo[it] = ((unsigned)(z * NB + b0 + it) * SEGS + (unsigned)s) * 256u
                 + (unsigned)(lane * 4);
    }

    float acc0 = 0.0f, acc1 = 0.0f, acc2 = 0.0f;

    // ---- software pipeline: one dwordx4 per lane per pair ----
    uint4 tb[2];
    tb[0] = *(const uint4*)(PC + rowo[0]);

    #pragma unroll
    for (int it = 0; it < PPW; ++it) {
        if (it + 1 < PPW) tb[(it + 1) & 1] = *(const uint4*)(PC + rowo[it + 1]);
        uint4 tt = tb[it & 1];
        float r = rr[it];
        float T0 = rcomb(tt.x, r);
        float T1 = rcomb(tt.y, r);
        float T2 = rcomb(tt.z, r);
        float T3 = rcomb(tt.w, r);

        float nx = nxa[it], ny = nya[it], nz = nza[it];
        float Y1_0 = c1sh * ny, Y1_1 = c1sh * nz, Y1_2 = c1sh * nx;
        float zf = zfa[it];

        if (l0) {
            // out(l0,u) partial: T0 + Y1 . T1vec
            float sl0 = T0;
            sl0 = fmaf(Y1_0, T1, sl0);
            sl0 = fmaf(Y1_1, T2, sl0);
            sl0 = fmaf(Y1_2, T3, sl0);
            acc0 = fmaf(sl0, zf, acc0);
        } else if (part == 0) {
            // T0 (C) + T1vec (D) terms of s_xyz
            float px = fmaf(Y1_0, T0, T1);
            float py = fmaf(Y1_1, T0, T2);
            float pz = fmaf(Y1_2, T0, T3);
            acc0 = fmaf(px, zf, acc0);
            acc1 = fmaf(py, zf, acc1);
            acc2 = fmaf(pz, zf, acc2);
        } else if (part == 1) {
            // T2vec (E) cross terms
            float px = fmaf(Y1_2, T1, -Y1_1 * T2);
            float py = fmaf(Y1_0, T2, -Y1_2 * T0);
            float pz = fmaf(Y1_1, T0, -Y1_0 * T1);
            acc0 = fmaf(px, zf, acc0);
            acc1 = fmaf(py, zf, acc1);
            acc2 = fmaf(pz, zf, acc2);
        } else {
            // T3vec (F) l=2 terms
            float Y2_0 = c21 * nx * ny;
            float Y2_1 = c21 * ny * nz;
            float Y2_2 = c22 * fmaf(3.0f, nz * nz, -1.0f);
            float Y2_3 = c21 * nx * nz;
            float Y2_4 = c23 * (nx * nx - ny * ny);
            float za_ = is10 * Y2_0, zb_ = is10 * Y2_1, zc_ = is10 * Y2_3;
            float zd_ = is30 * Y2_2, ze_ = is10 * Y2_4;
            float px = fmaf(-(zd_ + ze_), T0, fmaf(zb_, T1, za_ * T2));
            float py = fmaf(zb_, T0, fmaf(2.0f * zd_, T1, zc_ * T2));
            float pz = fmaf(za_, T0, fmaf(zc_, T1, (ze_ - zd_) * T2));
            acc0 = fmaf(px, zf, acc0);
            acc1 = fmaf(py, zf, acc1);
            acc2 = fmaf(pz, zf, acc2);
        }
    }

    // ---- combine the 3 l1 parts (lanes 16+3u+{0,1,2}) ----
    float ax = acc0 + __shfl_down(acc0, 1) + __shfl_down(acc0, 2);
    float ay = acc1 + __shfl_down(acc1, 1) + __shfl_down(acc1, 2);
    float az = acc2 + __shfl_down(acc2, 1) + __shfl_down(acc2, 2);
    if (l0) {
        sAcc[wv][lane] = acc0;
    } else if (part == 0) {
        int ob = 16 + u * 3;
        sAcc[wv][ob]     = ax;
        sAcc[wv][ob + 1] = ay;
        sAcc[wv][ob + 2] = az;
    }
    __syncthreads();
    if (threadIdx.x < 64) {
        float sum = sAcc[0][threadIdx.x] + sAcc[1][threadIdx.x]
                  + sAcc[2][threadIdx.x] + sAcc[3][threadIdx.x];
        sum *= mask[za];
        atomicAdd(&out[(size_t)za * 64 + threadIdx.x], sum);
    }
}

extern "C" void kernel_launch(void* const* d_in, const int* in_sizes, int n_in,
                              void* d_out, int out_size, void* d_ws, size_t ws_size,
                              hipStream_t stream) {
    (void)in_sizes; (void)n_in; (void)ws_size; (void)out_size;
    const float* feat = (const float*)d_in[0];
    const float* geom = (const float*)d_in[1];
    const float* mask = (const float*)d_in[2];
    const float* W1   = (const float*)d_in[3];
    const float* b1   = (const float*)d_in[4];
    const float* W2   = (const float*)d_in[5];
    const float* b2   = (const float*)d_in[6];
    float* out = (float*)d_out;
    float* ws  = (float*)d_ws;                 // PC (21.3MB) | SWB (2.1MB)
    unsigned int* PC = (unsigned int*)d_ws;

    k_sw  <<<336, 256, 0, stream>>>(W1, b1, W2, b2, ws, out);  // 256 table + 80 zero
    k_pc3 <<<512, 256, 0, stream>>>(feat, ws, PC);
    k_main<<<2 * NA * CW / 4, 256, 0, stream>>>(geom, mask, PC, out);
}

// Round 5
// 94.969 us; speedup vs baseline: 1.3685x; 1.0120x over previous
//
#include <hip/hip_runtime.h>
#include <hip/hip_fp16.h>
#include <math.h>

#define NPATH 1536
#define SEGS  65        // 0..64 active-channel counts
#define NB    160
#define NA    160
#define CW    32        // chunks (waves) per (z,a)
#define PPW   5         // pairs per wave = NB/CW

// d_ws layout:
//   [0, 21.3MB)  PC[zb][seg][256 u32]  — packed {fp16 slope | fp16 icpt}
//   [21.3MB, +2.6MB) SWB2 — feature-independent per-slot segment table,
//     laid out for fully-coalesced wave reads in k_pc3:
//     float4 index (T = tg*16+tl, s = k*16+sgrp, j = v-pair):
//       flat4 = (((tg*5 + k)*8 + j)*16 + sgrp)*16 + tl
//     float4 = {sw(v=2j), sb(2j), sw(2j+1), sb(2j+1)}  (k=4: only sgrp=0 used)
// slot t = lane*4 + j (k_main reads uint4 per lane):
//   lane  0..15 (l0 task u=lane): j0 = A(u)->T0 ; j1..3 = B(u,xyz)->T1c
//   lane 16..63 (l1 task u=(lane-16)/3, part=(lane-16)%3):
//     part0: j0 = C(u)->T0 ; j1..3 = D(u,xyz)->T1c
//     part1: j0..2 = E(u,xyz)->T2c ; j3 pad
//     part2: j0..2 = F(u,xyz)->T3c ; j3 pad
#define PC_U32S   (320 * SEGS * 256)            // 5,324,800 u32
#define SWB_OFF   PC_U32S                        // float offset into ws

__device__ float dg_thr[64];

#define SCL_A 0.17677669529663687f
#define SCL_B 0.6266570686577502f
#define SCL_C 0.2558286876965162f
#define SCL_D 0.125f
#define SCL_E 0.3133285343288751f
#define SCL_F 0.7674950309598664f

// slot t -> (path base, path stride, feature component, folded scale).
// comp == -1 -> feature f[v]; else f[16 + 3v + comp]. Pad slots: scl = 0.
static __device__ __forceinline__ void slot_map(int t, int& pbase, int& pstr,
                                                int& comp, float& scl) {
    int lane4 = t >> 2, j = t & 3;
    pbase = 0; pstr = 1; comp = -1; scl = 0.0f;
    if (lane4 < 16) {
        if (j == 0) { pbase = lane4 * 16;       scl = SCL_A; }
        else        { pbase = 256 + lane4 * 16; comp = j - 1; scl = SCL_B; }
    } else {
        int lu = lane4 - 16, u = lu / 3, part = lu - u * 3;
        if (part == 0) {
            if (j == 0) { pbase = 512 + u * 16;                       scl = SCL_C; }
            else        { pbase = 768 + u * 48; pstr = 3; comp = j - 1; scl = SCL_D; }
        } else if (part == 1) {
            if (j < 3)  { pbase = 768 + u * 48 + 1; pstr = 3; comp = j; scl = SCL_E; }
        } else {
            if (j < 3)  { pbase = 768 + u * 48 + 2; pstr = 3; comp = j; scl = SCL_F; }
        }
    }
}

// blocks 0..255: one per slot t. Staging: thread (c=tid>>2, vq=tid&3) loads
// 4 W2 values from its c-row (16 rows per wave-instr, sector-packed — vs the
// old 64-way scatter). Compute: thread (v, s-quad) masked base sum + prefix.
// blocks 256..335: zero d_out.
__global__ __launch_bounds__(256) void k_sw(const float* __restrict__ W1,
                                            const float* __restrict__ b1,
                                            const float* __restrict__ W2,
                                            const float* __restrict__ b2,
                                            float* __restrict__ ws,
                                            float* __restrict__ out) {
    int bid = blockIdx.x, tid = threadIdx.x;
    if (bid >= 256) {                       // 80 blocks x 256 = 20480 floats
        out[(bid - 256) * 256 + tid] = 0.0f;
        return;
    }
    int t = bid;

    __shared__ float  tvS[64];
    __shared__ float4 chS[64];              // {wPos, wNeg, bSel, bUnsel}
    __shared__ int    rkS[64];
    __shared__ int    ordS[64];
    __shared__ float  dwS[64], dbS[64], b2S[16];
    __shared__ float  W2t[16][65];          // pad 65

    if (tid < 64) {
        float w = W1[tid], bb = b1[tid];
        tvS[tid] = (w != 0.0f) ? (-bb / w) : __builtin_inff();
    }
    __syncthreads();
    if (tid < 64) {
        float mine = tvS[tid];
        int rank = 0;
        for (int j2 = 0; j2 < 64; ++j2) {
            float o = tvS[j2];
            rank += (o < mine || (o == mine && j2 < tid)) ? 1 : 0;
        }
        float w = W1[tid], bb = b1[tid];
        // sel (= rank < s): channel is in the "threshold passed" set.
        //   w>0: active iff sel;  w<0: active iff !sel;  w==0: active iff b>0
        chS[tid] = make_float4((w > 0.0f) ? w : 0.0f,
                               (w < 0.0f) ? w : 0.0f,
                               (w > 0.0f) ? bb : 0.0f,
                               (w < 0.0f) ? bb : ((w == 0.0f && bb > 0.0f) ? bb : 0.0f));
        rkS[tid] = rank;
        // step s -> s+1 flips the channel with rank s: w>0 adds, w<0 removes
        ordS[rank] = tid;
        dwS[rank]  = fabsf(w);
        dbS[rank]  = (w > 0.0f) ? bb : ((w < 0.0f) ? -bb : 0.0f);
        if (t == 0) dg_thr[tid] = mine;
    }

    int pbase, pstr, comp; float scl;
    slot_map(t, pbase, pstr, comp, scl);
    (void)comp;
    int cs = tid >> 2, vq = tid & 3;        // 16 c-rows per wave-instr
    #pragma unroll
    for (int i = 0; i < 4; ++i) {
        int v = vq * 4 + i;
        W2t[v][cs] = scl * W2[(size_t)cs * NPATH + pbase + v * pstr];
    }
    if (tid < 16) b2S[tid] = scl * b2[pbase + tid * pstr];
    __syncthreads();

    int v = tid & 15, sq = tid >> 4;        // 16 v x 16 s-quads
    int s0 = sq * 4;
    float sw = 0.0f, sb = 0.0f;
    #pragma unroll 8
    for (int cc = 0; cc < 64; ++cc) {
        float  w2 = W2t[v][cc];
        float4 ch = chS[cc];                // broadcast
        bool sel = rkS[cc] < s0;
        sw = fmaf(sel ? ch.x : ch.y, w2, sw);
        sb = fmaf(sel ? ch.z : ch.w, w2, sb);
    }
    sb += b2S[v];

    // SWB2 store address for (t, s, v): see layout comment.
    int tg = t >> 4, tl = t & 15, jj = v >> 1, half = v & 1;
    float2* swb = (float2*)(ws + SWB_OFF);
    int ns = (sq == 15) ? 5 : 4;            // sq 15 also writes s=64
    for (int i = 0; i < ns; ++i) {
        int s = s0 + i, k = s >> 4, sg = s & 15;
        int flat4 = (((tg * 5 + k) * 8 + jj) * 16 + sg) * 16 + tl;
        swb[flat4 * 2 + half] = make_float2(sw, sb);
        if (i + 1 < ns) {
            float w2s = W2t[v][ordS[s]];
            sw = fmaf(dwS[s], w2s, sw);
            sb = fmaf(dbS[s], w2s, sb);
        }
    }
}

// Tiny batched GEMM: PC[zb][s][T] = pack(sum_v f*SW, sum_v f*SB).
// grid = 16 t-groups x 32 zb-tiles (tile=10). SWB2 layout makes each of the
// 8 q-loads a fully-contiguous 1KB wave transaction (16 tl x 4 sgrp lanes).
__global__ __launch_bounds__(256) void k_pc3(const float* __restrict__ feat,
                                             const float* __restrict__ ws,
                                             unsigned int* __restrict__ PC) {
    int tg = blockIdx.x & 15, zt = blockIdx.x >> 4;
    int zb0 = zt * 10;

    __shared__ __align__(16) float fS[10][64];   // [zb][ct*16 + v]
    #pragma unroll
    for (int i = 0; i < 3; ++i) {
        int idx = threadIdx.x + i * 256;
        if (idx < 640) {
            int row = idx >> 6, fi = idx & 63;
            float val = feat[(size_t)(zb0 + row) * 64 + fi];
            int dest;
            if (fi < 16) dest = fi;
            else { int q = (fi - 16) / 3, c3 = (fi - 16) - 3 * q; dest = (c3 + 1) * 16 + q; }
            fS[row][dest] = val;
        }
    }
    __syncthreads();

    int tl = threadIdx.x & 15, sgrp = threadIdx.x >> 4;
    int T = tg * 16 + tl;
    int pbase, pstr, comp; float scl;
    slot_map(T, pbase, pstr, comp, scl);
    (void)pbase; (void)pstr; (void)scl;
    const float* fb = &fS[0][(comp + 1) * 16];
    const float4* swb = (const float4*)(ws + SWB_OFF);

    for (int k = 0; k < 5; ++k) {
        int s = k * 16 + sgrp;
        if (s >= SEGS) break;                // only k=4, sgrp>0 exits here
        int base4 = (((tg * 5 + k) * 8) * 16 + sgrp) * 16 + tl;
        float4 q0 = swb[base4];
        float4 q1 = swb[base4 + 256], q2 = swb[base4 + 512], q3 = swb[base4 + 768];
        float4 q4 = swb[base4 + 1024], q5 = swb[base4 + 1280];
        float4 q6 = swb[base4 + 1536], q7 = swb[base4 + 1792];
        unsigned int* op = PC + (size_t)zb0 * (SEGS * 256) + (size_t)s * 256 + T;
        #pragma unroll 2
        for (int zb = 0; zb < 10; ++zb) {
            const float4* fp = (const float4*)(fb + zb * 64);
            float4 f0 = fp[0], f1 = fp[1], f2 = fp[2], f3 = fp[3];
            float sw = q0.x * f0.x,          sb = q0.y * f0.x;
            sw = fmaf(q0.z, f0.y, sw);  sb = fmaf(q0.w, f0.y, sb);
            sw = fmaf(q1.x, f0.z, sw);  sb = fmaf(q1.y, f0.z, sb);
            sw = fmaf(q1.z, f0.w, sw);  sb = fmaf(q1.w, f0.w, sb);
            sw = fmaf(q2.x, f1.x, sw);  sb = fmaf(q2.y, f1.x, sb);
            sw = fmaf(q2.z, f1.y, sw);  sb = fmaf(q2.w, f1.y, sb);
            sw = fmaf(q3.x, f1.z, sw);  sb = fmaf(q3.y, f1.z, sb);
            sw = fmaf(q3.z, f1.w, sw);  sb = fmaf(q3.w, f1.w, sb);
            sw = fmaf(q4.x, f2.x, sw);  sb = fmaf(q4.y, f2.x, sb);
            sw = fmaf(q4.z, f2.y, sw);  sb = fmaf(q4.w, f2.y, sb);
            sw = fmaf(q5.x, f2.z, sw);  sb = fmaf(q5.y, f2.z, sb);
            sw = fmaf(q5.z, f2.w, sw);  sb = fmaf(q5.w, f2.w, sb);
            sw = fmaf(q6.x, f3.x, sw);  sb = fmaf(q6.y, f3.x, sb);
            sw = fmaf(q6.z, f3.y, sw);  sb = fmaf(q6.w, f3.y, sb);
            sw = fmaf(q7.x, f3.z, sw);  sb = fmaf(q7.y, f3.z, sb);
            sw = fmaf(q7.z, f3.w, sw);  sb = fmaf(q7.w, f3.w, sb);
            union { __half2 h; unsigned int u; } pk;
            pk.h = __halves2half2(__float2half(sw), __float2half(sb));
            op[(size_t)zb * (SEGS * 256)] = pk.u;
        }
    }
}

static __device__ __forceinline__ float rcomb(unsigned int v, float r) {
    union { unsigned int u; __half2 h; } cv; cv.u = v;
    return fmaf(r, __low2float(cv.h), __high2float(cv.h));
}

__global__ __launch_bounds__(256, 4) void k_main(const float* __restrict__ geom,
                                                 const float* __restrict__ mask,
                                                 const unsigned int* __restrict__ PC,
                                                 float* __restrict__ out) {
    int wv   = threadIdx.x >> 6;
    int lane = threadIdx.x & 63;
    int gw   = blockIdx.x * 4 + wv;     // 4 waves of a block share za
    int chunk = gw & (CW - 1);
    int za    = gw >> 5;                // z*160 + a
    int z     = za / NA;

    __shared__ float sAcc[4][64];

    bool l0 = lane < 16;
    int  u = 0, part = 0;
    if (!l0) { int lu = lane - 16; u = lu / 3; part = lu - u * 3; }
    float zft = l0 ? 1.4142135623730951f : 2.0f;   // zero-radius norm ratio
    float thrv = dg_thr[lane];

    const float is30 = 0.18257418583505536f;  // 1/sqrt(30)
    const float is10 = 0.31622776601683794f;  // 1/sqrt(10)
    const float c1sh = 0.4886025119029199f;
    const float c21 = 1.0925484305920792f, c22 = 0.31539156525252005f, c23 = 0.5462742152960396f;

    // ---- geometry / segment for all PPW pairs ----
    int b0 = chunk * PPW;
    float rr[PPW], nxa[PPW], nya[PPW], nza[PPW], zfa[PPW];
    unsigned int rowo[PPW];
    #pragma unroll
    for (int it = 0; it < PPW; ++it) {
        const float* g = geom + ((size_t)za * NB + b0 + it) * 3;
        float gx = g[0], gy = g[1], gz = g[2];
        float r = sqrtf(gx * gx + gy * gy + gz * gz);
        bool zr = (r == 0.0f);
        float inv = zr ? 1.0f : (1.0f / r);
        nxa[it] = gx * inv; nya[it] = gy * inv; nza[it] = gz * inv;
        rr[it] = r;
        zfa[it] = zr ? zft : 1.0f;
        unsigned long long bm = __ballot(thrv < r);
        int s = __popcll(bm);
        rowo[it] = ((unsigned)(z * NB + b0 + it) * SEGS + (unsigned)s) * 256u
                 + (unsigned)(lane * 4);
    }

    float acc0 = 0.0f, acc1 = 0.0f, acc2 = 0.0f;

    // ---- software pipeline: one dwordx4 per lane per pair ----
    uint4 tb[2];
    tb[0] = *(const uint4*)(PC + rowo[0]);

    #pragma unroll
    for (int it = 0; it < PPW; ++it) {
        if (it + 1 < PPW) tb[(it + 1) & 1] = *(const uint4*)(PC + rowo[it + 1]);
        uint4 tt = tb[it & 1];
        float r = rr[it];
        float T0 = rcomb(tt.x, r);
        float T1 = rcomb(tt.y, r);
        float T2 = rcomb(tt.z, r);
        float T3 = rcomb(tt.w, r);

        float nx = nxa[it], ny = nya[it], nz = nza[it];
        float Y1_0 = c1sh * ny, Y1_1 = c1sh * nz, Y1_2 = c1sh * nx;
        float zf = zfa[it];

        if (l0) {
            // out(l0,u) partial: T0 + Y1 . T1vec
            float sl0 = T0;
            sl0 = fmaf(Y1_0, T1, sl0);
            sl0 = fmaf(Y1_1, T2, sl0);
            sl0 = fmaf(Y1_2, T3, sl0);
            acc0 = fmaf(sl0, zf, acc0);
        } else if (part == 0) {
            // T0 (C) + T1vec (D) terms of s_xyz
            float px = fmaf(Y1_0, T0, T1);
            float py = fmaf(Y1_1, T0, T2);
            float pz = fmaf(Y1_2, T0, T3);
            acc0 = fmaf(px, zf, acc0);
            acc1 = fmaf(py, zf, acc1);
            acc2 = fmaf(pz, zf, acc2);
        } else if (part == 1) {
            // T2vec (E) cross terms
            float px = fmaf(Y1_2, T1, -Y1_1 * T2);
            float py = fmaf(Y1_0, T2, -Y1_2 * T0);
            float pz = fmaf(Y1_1, T0, -Y1_0 * T1);
            acc0 = fmaf(px, zf, acc0);
            acc1 = fmaf(py, zf, acc1);
            acc2 = fmaf(pz, zf, acc2);
        } else {
            // T3vec (F) l=2 terms
            float Y2_0 = c21 * nx * ny;
            float Y2_1 = c21 * ny * nz;
            float Y2_2 = c22 * fmaf(3.0f, nz * nz, -1.0f);
            float Y2_3 = c21 * nx * nz;
            float Y2_4 = c23 * (nx * nx - ny * ny);
            float za_ = is10 * Y2_0, zb_ = is10 * Y2_1, zc_ = is10 * Y2_3;
            float zd_ = is30 * Y2_2, ze_ = is10 * Y2_4;
            float px = fmaf(-(zd_ + ze_), T0, fmaf(zb_, T1, za_ * T2));
            float py = fmaf(zb_, T0, fmaf(2.0f * zd_, T1, zc_ * T2));
            float pz = fmaf(za_, T0, fmaf(zc_, T1, (ze_ - zd_) * T2));
            acc0 = fmaf(px, zf, acc0);
            acc1 = fmaf(py, zf, acc1);
            acc2 = fmaf(pz, zf, acc2);
        }
    }

    // ---- combine the 3 l1 parts (lanes 16+3u+{0,1,2}) ----
    float ax = acc0 + __shfl_down(acc0, 1) + __shfl_down(acc0, 2);
    float ay = acc1 + __shfl_down(acc1, 1) + __shfl_down(acc1, 2);
    float az = acc2 + __shfl_down(acc2, 1) + __shfl_down(acc2, 2);
    if (l0) {
        sAcc[wv][lane] = acc0;
    } else if (part == 0) {
        int ob = 16 + u * 3;
        sAcc[wv][ob]     = ax;
        sAcc[wv][ob + 1] = ay;
        sAcc[wv][ob + 2] = az;
    }
    __syncthreads();
    if (threadIdx.x < 64) {
        float sum = sAcc[0][threadIdx.x] + sAcc[1][threadIdx.x]
                  + sAcc[2][threadIdx.x] + sAcc[3][threadIdx.x];
        sum *= mask[za];
        atomicAdd(&out[(size_t)za * 64 + threadIdx.x], sum);
    }
}

extern "C" void kernel_launch(void* const* d_in, const int* in_sizes, int n_in,
                              void* d_out, int out_size, void* d_ws, size_t ws_size,
                              hipStream_t stream) {
    (void)in_sizes; (void)n_in; (void)ws_size; (void)out_size;
    const float* feat = (const float*)d_in[0];
    const float* geom = (const float*)d_in[1];
    const float* mask = (const float*)d_in[2];
    const float* W1   = (const float*)d_in[3];
    const float* b1   = (const float*)d_in[4];
    const float* W2   = (const float*)d_in[5];
    const float* b2   = (const float*)d_in[6];
    float* out = (float*)d_out;
    float* ws  = (float*)d_ws;                 // PC (21.3MB) | SWB2 (2.6MB)
    unsigned int* PC = (unsigned int*)d_ws;

    k_sw  <<<336, 256, 0, stream>>>(W1, b1, W2, b2, ws, out);  // 256 table + 80 zero
    k_pc3 <<<512, 256, 0, stream>>>(feat, ws, PC);
    k_main<<<2 * NA * CW / 4, 256, 0, stream>>>(geom, mask, PC, out);
}